// Round 7
// baseline (403.521 us; speedup 1.0000x reference)
//
#include <hip/hip_runtime.h>

#define HWp 9216
#define CD 128
#define RC 64
#define NB 2
#define KSPLIT 8
#define LOG2E 1.4426950408889634f
#define THR_LOG2 11.0f

typedef short s16x8 __attribute__((ext_vector_type(8)));
typedef unsigned short u16x8 __attribute__((ext_vector_type(8)));
typedef float fx4 __attribute__((ext_vector_type(4)));

__device__ __forceinline__ unsigned short f2bf(float f) {
    union { float f; unsigned int u; } cv; cv.f = f;
    unsigned int u = cv.u;
    u += 0x7FFFu + ((u >> 16) & 1u);
    return (unsigned short)(u >> 16);
}

__device__ __forceinline__ float fexp2(float x) {
    float r; asm("v_exp_f32 %0, %1" : "=v"(r) : "v"(x)); return r;
}

__device__ __forceinline__ unsigned int cvt_pk_bf16(float lo, float hi) {
    unsigned int r; asm("v_cvt_pk_bf16_f32 %0, %1, %2" : "=v"(r) : "v"(lo), "v"(hi)); return r;
}

__device__ __forceinline__ const float* uniform_ptr(const float* p) {
    unsigned long long v = (unsigned long long)(uintptr_t)p;
    unsigned int lo = __builtin_amdgcn_readfirstlane((unsigned int)v);
    unsigned int hi = __builtin_amdgcn_readfirstlane((unsigned int)(v >> 32));
    return (const float*)(uintptr_t)(((unsigned long long)hi << 32) | lo);
}

// Projections: E1[p][64] (log2e-scaled), E2[p][64], A[c][p], all bf16.
// R2-VERBATIM (passing): grid (144, NB, 4); block 256 = 4 waves x 16 rows.
__global__ __launch_bounds__(256) void proj_kernel(
    const float* __restrict__ x,
    const float* __restrict__ w1, const float* __restrict__ b1, const float* __restrict__ a1,
    const float* __restrict__ w2, const float* __restrict__ b2, const float* __restrict__ a2,
    const float* __restrict__ wa, const float* __restrict__ ba, const float* __restrict__ aa,
    unsigned short* __restrict__ e1, unsigned short* __restrict__ e2,
    unsigned short* __restrict__ av)
{
    const int n = blockIdx.y;
    const int p0 = blockIdx.x * 64;
    const int wv = threadIdx.x >> 6;
    const int lane = threadIdx.x & 63;
    const int p = p0 + lane;
    const int row0 = blockIdx.z * 64 + wv * 16;   // 0..255 in [e1(64) | e2(64) | av(128)]
    const float* __restrict__ xb = x + (size_t)n * CD * HWp;

    const float* W; const float* B; const float* A; int r0; int mode; float oscale = 1.0f;
    if (row0 < 64)       { W = w1; B = b1; A = a1; r0 = row0;       mode = 0; oscale = LOG2E; }
    else if (row0 < 128) { W = w2; B = b2; A = a2; r0 = row0 - 64;  mode = 1; }
    else                 { W = wa; B = ba; A = aa; r0 = row0 - 128; mode = 2; }
    W = uniform_ptr(W); B = uniform_ptr(B);
    const float slope = A[0];

    float acc[16];
#pragma unroll
    for (int j = 0; j < 16; ++j) acc[j] = B[r0 + j];
    for (int cc = 0; cc < 4; ++cc) {
        float xr[32];
#pragma unroll
        for (int i = 0; i < 32; ++i) xr[i] = xb[(size_t)(cc * 32 + i) * HWp + p];
#pragma unroll
        for (int j = 0; j < 16; ++j) {
            const float* Wr = W + (size_t)(r0 + j) * CD + cc * 32;
            float a = acc[j];
#pragma unroll
            for (int i = 0; i < 32; ++i) a = __builtin_fmaf(Wr[i], xr[i], a);
            acc[j] = a;
        }
    }
#pragma unroll
    for (int j = 0; j < 16; ++j) {
        float v = acc[j];
        acc[j] = (v >= 0.f ? v : slope * v) * oscale;
    }
    if (mode < 2) {
        u16x8 s0, s1;
#pragma unroll
        for (int j = 0; j < 8; ++j) { s0[j] = f2bf(acc[j]); s1[j] = f2bf(acc[8 + j]); }
        unsigned short* dst = (mode == 0 ? e1 : e2) + ((size_t)n * HWp + p) * RC + r0;
        *(u16x8*)(dst) = s0;
        *(u16x8*)(dst + 8) = s1;
    } else {
#pragma unroll
        for (int j = 0; j < 16; ++j)
            av[((size_t)n * CD + r0 + j) * HWp + p] = f2bf(acc[j]);
    }
}

// Flash attention, R2 structure widened: block = 64 queries (qc=4 per wave),
// 8 waves key-split (1152 keys each), LDS merge. 288 blocks x 512 thr.
// Same 12 gather instrs per step now serve 64 queries (2x R2 efficiency).
__global__ __launch_bounds__(512, 2) void attn_kernel(
    const unsigned short* __restrict__ e1,
    const unsigned short* __restrict__ e2,
    const unsigned short* __restrict__ av,
    float* __restrict__ out)
{
    const int wv = threadIdx.x >> 6;
    const int lane = threadIdx.x & 63;
    const int g = lane >> 4;
    const int l15 = lane & 15;

    // XCD swizzle: batch 0 -> XCDs 0-3, batch 1 -> XCDs 4-7 (L2 working-set fit)
    const int bid = blockIdx.x;
    const int xcd = bid & 7;
    const int n = xcd >> 2;
    const int qslot = (xcd & 3) * 36 + (bid >> 3);   // [0,144)
    const int qb = qslot * 64;

    const unsigned short* __restrict__ E1 = e1 + (size_t)n * HWp * RC;
    const unsigned short* __restrict__ E2 = e2 + (size_t)n * HWp * RC;
    const unsigned short* __restrict__ AV = av + (size_t)n * CD * HWp;

    // Q fragments (B operand): col = query = l15, k = channel = ch*32 + g*8 + j
    s16x8 qf[4][2];
#pragma unroll
    for (int qc = 0; qc < 4; ++qc)
#pragma unroll
        for (int ch = 0; ch < 2; ++ch)
            qf[qc][ch] = *(const s16x8*)(E1 + ((size_t)(qb + qc * 16 + l15)) * RC + ch * 32 + g * 8);

    s16x8 ones;
#pragma unroll
    for (int j = 0; j < 8; ++j) ones[j] = (short)0x3F80;   // bf16 1.0

    fx4 oacc[4][8];
    fx4 lacc[4];
#pragma unroll
    for (int qc = 0; qc < 4; ++qc) {
        lacc[qc] = (fx4){0.f, 0.f, 0.f, 0.f};
#pragma unroll
        for (int ct = 0; ct < 8; ++ct) oacc[qc][ct] = (fx4){0.f, 0.f, 0.f, 0.f};
    }
    float m_run[4] = {-1e30f, -1e30f, -1e30f, -1e30f};

    // key-row permutation so P regs land on PV B-frag layout (k = g*8+j)
    const int rowp = ((l15 >> 2) << 3) + (l15 & 3);
    const int kbase = wv * (HWp / KSPLIT);

    union { s16x8 v; unsigned int w[4]; } pf[4];

    for (int kt = 0; kt < (HWp / KSPLIT) / 32; ++kt) {
        const int k0 = kbase + kt * 32;
        s16x8 kf[2][2];
#pragma unroll
        for (int h = 0; h < 2; ++h)
#pragma unroll
            for (int ch = 0; ch < 2; ++ch)
                kf[h][ch] = *(const s16x8*)(E2 + (size_t)(k0 + rowp + 4 * h) * RC + ch * 32 + g * 8);

        // process queries in two pairs to limit live S registers
#pragma unroll
        for (int qp = 0; qp < 4; qp += 2) {
            fx4 s[2][2];
#pragma unroll
            for (int d = 0; d < 2; ++d)
#pragma unroll
                for (int h = 0; h < 2; ++h) {
                    fx4 a = (fx4){0.f, 0.f, 0.f, 0.f};
                    a = __builtin_amdgcn_mfma_f32_16x16x32_bf16(kf[h][0], qf[qp + d][0], a, 0, 0, 0);
                    a = __builtin_amdgcn_mfma_f32_16x16x32_bf16(kf[h][1], qf[qp + d][1], a, 0, 0, 0);
                    s[d][h] = a;
                }
#pragma unroll
            for (int d = 0; d < 2; ++d) {
                const int qc = qp + d;
                float tmax = s[d][0][0];
#pragma unroll
                for (int h = 0; h < 2; ++h)
#pragma unroll
                    for (int r = 0; r < 4; ++r) tmax = fmaxf(tmax, s[d][h][r]);
                tmax = fmaxf(tmax, __shfl_xor(tmax, 16));
                tmax = fmaxf(tmax, __shfl_xor(tmax, 32));
                if (!__all(tmax - m_run[qc] <= THR_LOG2)) {   // defer-max (T13)
                    float mn = fmaxf(m_run[qc], tmax);
                    float sc = fexp2(m_run[qc] - mn);
                    m_run[qc] = mn;
                    lacc[qc][0] *= sc; lacc[qc][1] *= sc; lacc[qc][2] *= sc; lacc[qc][3] *= sc;
#pragma unroll
                    for (int ct = 0; ct < 8; ++ct) {
                        oacc[qc][ct][0] *= sc; oacc[qc][ct][1] *= sc;
                        oacc[qc][ct][2] *= sc; oacc[qc][ct][3] *= sc;
                    }
                }
                const float m = m_run[qc];
                float p0 = fexp2(s[d][0][0] - m);
                float p1 = fexp2(s[d][0][1] - m);
                float p2 = fexp2(s[d][0][2] - m);
                float p3 = fexp2(s[d][0][3] - m);
                float p4 = fexp2(s[d][1][0] - m);
                float p5 = fexp2(s[d][1][1] - m);
                float p6 = fexp2(s[d][1][2] - m);
                float p7 = fexp2(s[d][1][3] - m);
                pf[qc].w[0] = cvt_pk_bf16(p0, p1);
                pf[qc].w[1] = cvt_pk_bf16(p2, p3);
                pf[qc].w[2] = cvt_pk_bf16(p4, p5);
                pf[qc].w[3] = cvt_pk_bf16(p6, p7);
                // l via ones-row MFMA (rescale applies automatically with oacc)
                lacc[qc] = __builtin_amdgcn_mfma_f32_16x16x32_bf16(ones, pf[qc].v, lacc[qc], 0, 0, 0);
            }
        }

        // PV: A = assembly tile [16 c x 32 keys], B = P ; af reused across 4 q-chunks
#pragma unroll
        for (int ct = 0; ct < 8; ++ct) {
            s16x8 a = *(const s16x8*)(AV + (size_t)(ct * 16 + l15) * HWp + k0 + g * 8);
            oacc[0][ct] = __builtin_amdgcn_mfma_f32_16x16x32_bf16(a, pf[0].v, oacc[0][ct], 0, 0, 0);
            oacc[1][ct] = __builtin_amdgcn_mfma_f32_16x16x32_bf16(a, pf[1].v, oacc[1][ct], 0, 0, 0);
            oacc[2][ct] = __builtin_amdgcn_mfma_f32_16x16x32_bf16(a, pf[2].v, oacc[2][ct], 0, 0, 0);
            oacc[3][ct] = __builtin_amdgcn_mfma_f32_16x16x32_bf16(a, pf[3].v, oacc[3][ct], 0, 0, 0);
        }
    }

    // ---- cross-wave combine (key-split), R2 scheme widened to 64 queries ----
    __shared__ float OA[64][CD + 4];
    __shared__ float MM[KSPLIT][64];
    __shared__ float LL[KSPLIT][64];
    __shared__ float LG[64];

    if (g == 0) {
#pragma unroll
        for (int qc = 0; qc < 4; ++qc) {
            MM[wv][qc * 16 + l15] = m_run[qc];
            LL[wv][qc * 16 + l15] = lacc[qc][0];
        }
    }
    __syncthreads();
    float fsc[4];
#pragma unroll
    for (int qc = 0; qc < 4; ++qc) {
        int q = qc * 16 + l15;
        float mg = MM[0][q];
#pragma unroll
        for (int w = 1; w < KSPLIT; ++w) mg = fmaxf(mg, MM[w][q]);
        fsc[qc] = fexp2(m_run[qc] - mg);
    }
    if (threadIdx.x < 64) {
        int q = threadIdx.x;
        float mg = MM[0][q];
#pragma unroll
        for (int w = 1; w < KSPLIT; ++w) mg = fmaxf(mg, MM[w][q]);
        float ls = 0.f;
#pragma unroll
        for (int w = 0; w < KSPLIT; ++w) ls += fexp2(MM[w][q] - mg) * LL[w][q];
        LG[q] = ls;
    }
    for (int w = 0; w < KSPLIT; ++w) {
        if (wv == w) {
#pragma unroll
            for (int qc = 0; qc < 4; ++qc)
#pragma unroll
                for (int ct = 0; ct < 8; ++ct)
#pragma unroll
                    for (int r = 0; r < 4; ++r) {
                        int q = qc * 16 + l15;
                        int c = ct * 16 + g * 4 + r;
                        float v = oacc[qc][ct][r] * fsc[qc];
                        if (w == 0) OA[q][c] = v; else OA[q][c] += v;
                    }
        }
        __syncthreads();
    }
    {
        const int c = threadIdx.x >> 2;
        const int qh = (threadIdx.x & 3) * 16;
        float* __restrict__ dst = out + ((size_t)n * CD + c) * HWp + qb + qh;
#pragma unroll
        for (int j = 0; j < 16; ++j) dst[j] = OA[qh + j][c] / LG[qh + j];
    }
}

extern "C" void kernel_launch(void* const* d_in, const int* in_sizes, int n_in,
                              void* d_out, int out_size, void* d_ws, size_t ws_size,
                              hipStream_t stream) {
    const float* x  = (const float*)d_in[0];
    const float* w1 = (const float*)d_in[1];
    const float* b1 = (const float*)d_in[2];
    const float* a1 = (const float*)d_in[3];
    const float* w2 = (const float*)d_in[4];
    const float* b2 = (const float*)d_in[5];
    const float* a2 = (const float*)d_in[6];
    const float* wa = (const float*)d_in[7];
    const float* ba = (const float*)d_in[8];
    const float* aa = (const float*)d_in[9];
    float* out = (float*)d_out;

    char* ws = (char*)d_ws;
    unsigned short* e1 = (unsigned short*)ws;                 // [N][HW][64] bf16 (log2e-scaled)
    unsigned short* e2 = (unsigned short*)(ws + 2359296);     // [N][HW][64] bf16
    unsigned short* av = (unsigned short*)(ws + 4718592);     // [N][128][HW] bf16
    // total ws usage: 9,437,184 B (proven safe in R1/R2)

    dim3 pg(HWp / 64, NB, 4);
    proj_kernel<<<pg, 256, 0, stream>>>(x, w1, b1, a1, w2, b2, a2, wa, ba, aa, e1, e2, av);
    attn_kernel<<<dim3(288), 512, 0, stream>>>(e1, e2, av, out);
}

// Round 8
// 362.610 us; speedup vs baseline: 1.1128x; 1.1128x over previous
//
#include <hip/hip_runtime.h>

#define HWp 9216
#define CD 128
#define RC 64
#define NB 2
#define KSPLIT 8
#define LOG2E 1.4426950408889634f
#define THR_LOG2 11.0f

// fragment-layout strides (in shorts)
#define E2F_NSTR 589824     // (HWp/32) kb * 4 frags * 64 lanes * 8
#define AVF_NSTR 1179648    // (HWp/32) kb * 8 frags * 64 lanes * 8

typedef short s16x8 __attribute__((ext_vector_type(8)));
typedef unsigned short u16x8 __attribute__((ext_vector_type(8)));
typedef float fx4 __attribute__((ext_vector_type(4)));

__device__ __forceinline__ unsigned short f2bf(float f) {
    union { float f; unsigned int u; } cv; cv.f = f;
    unsigned int u = cv.u;
    u += 0x7FFFu + ((u >> 16) & 1u);
    return (unsigned short)(u >> 16);
}

__device__ __forceinline__ float fexp2(float x) {
    float r; asm("v_exp_f32 %0, %1" : "=v"(r) : "v"(x)); return r;
}

__device__ __forceinline__ unsigned int cvt_pk_bf16(float lo, float hi) {
    unsigned int r; asm("v_cvt_pk_bf16_f32 %0, %1, %2" : "=v"(r) : "v"(lo), "v"(hi)); return r;
}

__device__ __forceinline__ const float* uniform_ptr(const float* p) {
    unsigned long long v = (unsigned long long)(uintptr_t)p;
    unsigned int lo = __builtin_amdgcn_readfirstlane((unsigned int)v);
    unsigned int hi = __builtin_amdgcn_readfirstlane((unsigned int)(v >> 32));
    return (const float*)(uintptr_t)(((unsigned long long)hi << 32) | lo);
}

// Projections. E1[p][64] (log2e-scaled) row-major as before.
// E2 -> e2f fragment layout: ((kb*4 + h*2 + ch)*64 + g*16 + l15)*8 + j
//   holds E2[key = kb*32 + rowp(l15) + 4h][chan = ch*32 + g*8 + j]
// AV -> avf fragment layout: ((kb*8 + ct)*64 + g*16 + l15)*8 + j
//   holds AV[chan = ct*16 + l15][key = kb*32 + g*8 + j]
// Math/grid R2-VERBATIM: grid (144, NB, 4); block 256 = 4 waves x 16 rows.
__global__ __launch_bounds__(256) void proj_kernel(
    const float* __restrict__ x,
    const float* __restrict__ w1, const float* __restrict__ b1, const float* __restrict__ a1,
    const float* __restrict__ w2, const float* __restrict__ b2, const float* __restrict__ a2,
    const float* __restrict__ wa, const float* __restrict__ ba, const float* __restrict__ aa,
    unsigned short* __restrict__ e1, unsigned short* __restrict__ e2f,
    unsigned short* __restrict__ avf)
{
    const int n = blockIdx.y;
    const int p0 = blockIdx.x * 64;
    const int wv = threadIdx.x >> 6;
    const int lane = threadIdx.x & 63;
    const int p = p0 + lane;
    const int row0 = blockIdx.z * 64 + wv * 16;   // 0..255 in [e1(64) | e2(64) | av(128)]
    const float* __restrict__ xb = x + (size_t)n * CD * HWp;

    const float* W; const float* B; const float* A; int r0; int mode; float oscale = 1.0f;
    if (row0 < 64)       { W = w1; B = b1; A = a1; r0 = row0;       mode = 0; oscale = LOG2E; }
    else if (row0 < 128) { W = w2; B = b2; A = a2; r0 = row0 - 64;  mode = 1; }
    else                 { W = wa; B = ba; A = aa; r0 = row0 - 128; mode = 2; }
    W = uniform_ptr(W); B = uniform_ptr(B);
    const float slope = A[0];

    float acc[16];
#pragma unroll
    for (int j = 0; j < 16; ++j) acc[j] = B[r0 + j];
    for (int cc = 0; cc < 4; ++cc) {
        float xr[32];
#pragma unroll
        for (int i = 0; i < 32; ++i) xr[i] = xb[(size_t)(cc * 32 + i) * HWp + p];
#pragma unroll
        for (int j = 0; j < 16; ++j) {
            const float* Wr = W + (size_t)(r0 + j) * CD + cc * 32;
            float a = acc[j];
#pragma unroll
            for (int i = 0; i < 32; ++i) a = __builtin_fmaf(Wr[i], xr[i], a);
            acc[j] = a;
        }
    }
#pragma unroll
    for (int j = 0; j < 16; ++j) {
        float v = acc[j];
        acc[j] = (v >= 0.f ? v : slope * v) * oscale;
    }
    if (mode == 0) {
        u16x8 s0, s1;
#pragma unroll
        for (int j = 0; j < 8; ++j) { s0[j] = f2bf(acc[j]); s1[j] = f2bf(acc[8 + j]); }
        unsigned short* dst = e1 + ((size_t)n * HWp + p) * RC + r0;
        *(u16x8*)(dst) = s0;
        *(u16x8*)(dst + 8) = s1;
    } else if (mode == 1) {
        u16x8 s0, s1;
#pragma unroll
        for (int j = 0; j < 8; ++j) { s0[j] = f2bf(acc[j]); s1[j] = f2bf(acc[8 + j]); }
        const int kb = p >> 5, kk = p & 31;
        const int l15w = ((kk >> 3) << 2) | (kk & 3);
        const int hw = (kk >> 2) & 1;
        const int ch = r0 >> 5;
        const int gA = (r0 >> 3) & 3;
        unsigned short* dst = e2f + (size_t)n * E2F_NSTR
                            + ((size_t)((kb * 4 + hw * 2 + ch) * 64 + gA * 16 + l15w)) * 8;
        *(u16x8*)(dst) = s0;          // octet gA   (j = 0..7, chan r0+j)
        *(u16x8*)(dst + 128) = s1;    // octet gA+1 (chan r0+8+j)
    } else {
        const int kb = p >> 5, gw = (p >> 3) & 3, jj = p & 7;
        const int ct = r0 >> 4;
        unsigned short* base = avf + (size_t)n * AVF_NSTR
                             + ((size_t)((kb * 8 + ct) * 64 + gw * 16)) * 8 + jj;
#pragma unroll
        for (int j = 0; j < 16; ++j)       // l15 = j (chan r0+j), stride 8 shorts
            base[j * 8] = f2bf(acc[j]);
    }
}

// Flash attention, R7 structure VERBATIM except: kf/af loads now read the
// fragment-ordered e2f/avf buffers as contiguous 1KB bursts (per instr:
// lane*16B consecutive). Per step: 4KB (kf) + 8KB (af) sequential.
__global__ __launch_bounds__(512, 2) void attn_kernel(
    const unsigned short* __restrict__ e1,
    const unsigned short* __restrict__ e2f,
    const unsigned short* __restrict__ avf,
    float* __restrict__ out)
{
    const int wv = threadIdx.x >> 6;
    const int lane = threadIdx.x & 63;
    const int g = lane >> 4;
    const int l15 = lane & 15;

    // XCD swizzle: batch 0 -> XCDs 0-3, batch 1 -> XCDs 4-7
    const int bid = blockIdx.x;
    const int xcd = bid & 7;
    const int n = xcd >> 2;
    const int qslot = (xcd & 3) * 36 + (bid >> 3);   // [0,144)
    const int qb = qslot * 64;

    const unsigned short* __restrict__ E1 = e1 + (size_t)n * HWp * RC;
    const unsigned short* __restrict__ E2F = e2f + (size_t)n * E2F_NSTR;
    const unsigned short* __restrict__ AVF = avf + (size_t)n * AVF_NSTR;

    // Q fragments (B operand): col = query = l15, k = channel = ch*32 + g*8 + j
    s16x8 qf[4][2];
#pragma unroll
    for (int qc = 0; qc < 4; ++qc)
#pragma unroll
        for (int ch = 0; ch < 2; ++ch)
            qf[qc][ch] = *(const s16x8*)(E1 + ((size_t)(qb + qc * 16 + l15)) * RC + ch * 32 + g * 8);

    s16x8 ones;
#pragma unroll
    for (int j = 0; j < 8; ++j) ones[j] = (short)0x3F80;   // bf16 1.0

    fx4 oacc[4][8];
    fx4 lacc[4];
#pragma unroll
    for (int qc = 0; qc < 4; ++qc) {
        lacc[qc] = (fx4){0.f, 0.f, 0.f, 0.f};
#pragma unroll
        for (int ct = 0; ct < 8; ++ct) oacc[qc][ct] = (fx4){0.f, 0.f, 0.f, 0.f};
    }
    float m_run[4] = {-1e30f, -1e30f, -1e30f, -1e30f};

    const int kb0 = wv * (HWp / KSPLIT / 32);   // first key-block of this wave

    union { s16x8 v; unsigned int w[4]; } pf[4];

    for (int kt = 0; kt < (HWp / KSPLIT) / 32; ++kt) {
        const int kb = kb0 + kt;
        // kf fragments: 4 consecutive 1KB bursts
        s16x8 kf[2][2];
#pragma unroll
        for (int h = 0; h < 2; ++h)
#pragma unroll
            for (int ch = 0; ch < 2; ++ch)
                kf[h][ch] = *(const s16x8*)(E2F + ((size_t)((kb * 4 + h * 2 + ch) * 64 + lane)) * 8);

        // process queries in two pairs to limit live S registers
#pragma unroll
        for (int qp = 0; qp < 4; qp += 2) {
            fx4 s[2][2];
#pragma unroll
            for (int d = 0; d < 2; ++d)
#pragma unroll
                for (int h = 0; h < 2; ++h) {
                    fx4 a = (fx4){0.f, 0.f, 0.f, 0.f};
                    a = __builtin_amdgcn_mfma_f32_16x16x32_bf16(kf[h][0], qf[qp + d][0], a, 0, 0, 0);
                    a = __builtin_amdgcn_mfma_f32_16x16x32_bf16(kf[h][1], qf[qp + d][1], a, 0, 0, 0);
                    s[d][h] = a;
                }
#pragma unroll
            for (int d = 0; d < 2; ++d) {
                const int qc = qp + d;
                float tmax = s[d][0][0];
#pragma unroll
                for (int h = 0; h < 2; ++h)
#pragma unroll
                    for (int r = 0; r < 4; ++r) tmax = fmaxf(tmax, s[d][h][r]);
                tmax = fmaxf(tmax, __shfl_xor(tmax, 16));
                tmax = fmaxf(tmax, __shfl_xor(tmax, 32));
                if (!__all(tmax - m_run[qc] <= THR_LOG2)) {   // defer-max (T13)
                    float mn = fmaxf(m_run[qc], tmax);
                    float sc = fexp2(m_run[qc] - mn);
                    m_run[qc] = mn;
                    lacc[qc][0] *= sc; lacc[qc][1] *= sc; lacc[qc][2] *= sc; lacc[qc][3] *= sc;
#pragma unroll
                    for (int ct = 0; ct < 8; ++ct) {
                        oacc[qc][ct][0] *= sc; oacc[qc][ct][1] *= sc;
                        oacc[qc][ct][2] *= sc; oacc[qc][ct][3] *= sc;
                    }
                }
                const float m = m_run[qc];
                float p0 = fexp2(s[d][0][0] - m);
                float p1 = fexp2(s[d][0][1] - m);
                float p2 = fexp2(s[d][0][2] - m);
                float p3 = fexp2(s[d][0][3] - m);
                float p4 = fexp2(s[d][1][0] - m);
                float p5 = fexp2(s[d][1][1] - m);
                float p6 = fexp2(s[d][1][2] - m);
                float p7 = fexp2(s[d][1][3] - m);
                pf[qc].w[0] = cvt_pk_bf16(p0, p1);
                pf[qc].w[1] = cvt_pk_bf16(p2, p3);
                pf[qc].w[2] = cvt_pk_bf16(p4, p5);
                pf[qc].w[3] = cvt_pk_bf16(p6, p7);
                // l via ones-row MFMA (rescale applies automatically with oacc)
                lacc[qc] = __builtin_amdgcn_mfma_f32_16x16x32_bf16(ones, pf[qc].v, lacc[qc], 0, 0, 0);
            }
        }

        // PV: af fragments = 8 consecutive 1KB bursts; reused across 4 q-chunks
#pragma unroll
        for (int ct = 0; ct < 8; ++ct) {
            s16x8 a = *(const s16x8*)(AVF + ((size_t)((kb * 8 + ct) * 64 + lane)) * 8);
            oacc[0][ct] = __builtin_amdgcn_mfma_f32_16x16x32_bf16(a, pf[0].v, oacc[0][ct], 0, 0, 0);
            oacc[1][ct] = __builtin_amdgcn_mfma_f32_16x16x32_bf16(a, pf[1].v, oacc[1][ct], 0, 0, 0);
            oacc[2][ct] = __builtin_amdgcn_mfma_f32_16x16x32_bf16(a, pf[2].v, oacc[2][ct], 0, 0, 0);
            oacc[3][ct] = __builtin_amdgcn_mfma_f32_16x16x32_bf16(a, pf[3].v, oacc[3][ct], 0, 0, 0);
        }
    }

    // ---- cross-wave combine (key-split), R7-verbatim ----
    __shared__ float OA[64][CD + 4];
    __shared__ float MM[KSPLIT][64];
    __shared__ float LL[KSPLIT][64];
    __shared__ float LG[64];

    if (g == 0) {
#pragma unroll
        for (int qc = 0; qc < 4; ++qc) {
            MM[wv][qc * 16 + l15] = m_run[qc];
            LL[wv][qc * 16 + l15] = lacc[qc][0];
        }
    }
    __syncthreads();
    float fsc[4];
#pragma unroll
    for (int qc = 0; qc < 4; ++qc) {
        int q = qc * 16 + l15;
        float mg = MM[0][q];
#pragma unroll
        for (int w = 1; w < KSPLIT; ++w) mg = fmaxf(mg, MM[w][q]);
        fsc[qc] = fexp2(m_run[qc] - mg);
    }
    if (threadIdx.x < 64) {
        int q = threadIdx.x;
        float mg = MM[0][q];
#pragma unroll
        for (int w = 1; w < KSPLIT; ++w) mg = fmaxf(mg, MM[w][q]);
        float ls = 0.f;
#pragma unroll
        for (int w = 0; w < KSPLIT; ++w) ls += fexp2(MM[w][q] - mg) * LL[w][q];
        LG[q] = ls;
    }
    for (int w = 0; w < KSPLIT; ++w) {
        if (wv == w) {
#pragma unroll
            for (int qc = 0; qc < 4; ++qc)
#pragma unroll
                for (int ct = 0; ct < 8; ++ct)
#pragma unroll
                    for (int r = 0; r < 4; ++r) {
                        int q = qc * 16 + l15;
                        int c = ct * 16 + g * 4 + r;
                        float v = oacc[qc][ct][r] * fsc[qc];
                        if (w == 0) OA[q][c] = v; else OA[q][c] += v;
                    }
        }
        __syncthreads();
    }
    {
        const int c = threadIdx.x >> 2;
        const int qh = (threadIdx.x & 3) * 16;
        float* __restrict__ dst = out + ((size_t)n * CD + c) * HWp + qb + qh;
#pragma unroll
        for (int j = 0; j < 16; ++j) dst[j] = OA[qh + j][c] / LG[qh + j];
    }
}

extern "C" void kernel_launch(void* const* d_in, const int* in_sizes, int n_in,
                              void* d_out, int out_size, void* d_ws, size_t ws_size,
                              hipStream_t stream) {
    const float* x  = (const float*)d_in[0];
    const float* w1 = (const float*)d_in[1];
    const float* b1 = (const float*)d_in[2];
    const float* a1 = (const float*)d_in[3];
    const float* w2 = (const float*)d_in[4];
    const float* b2 = (const float*)d_in[5];
    const float* a2 = (const float*)d_in[6];
    const float* wa = (const float*)d_in[7];
    const float* ba = (const float*)d_in[8];
    const float* aa = (const float*)d_in[9];
    float* out = (float*)d_out;

    char* ws = (char*)d_ws;
    unsigned short* e1  = (unsigned short*)ws;                 // [N][HW][64] bf16 (log2e-scaled)
    unsigned short* e2f = (unsigned short*)(ws + 2359296);     // fragment layout, 2,359,296 B
    unsigned short* avf = (unsigned short*)(ws + 4718592);     // fragment layout, 4,718,592 B
    // total ws usage: 9,437,184 B (proven safe)

    dim3 pg(HWp / 64, NB, 4);
    proj_kernel<<<pg, 256, 0, stream>>>(x, w1, b1, a1, w2, b2, a2, wa, ba, aa, e1, e2f, avf);
    attn_kernel<<<dim3(288), 512, 0, stream>>>(e1, e2f, avf, out);
}

// Round 9
// 205.701 us; speedup vs baseline: 1.9617x; 1.7628x over previous
//
#include <hip/hip_runtime.h>

#define HWp 9216
#define CD 128
#define RC 64
#define NB 2
#define KSPLIT 8
#define NSTEPS 36           // key-blocks of 32 per wave
#define LOG2E 1.4426950408889634f
#define THR_LOG2 11.0f

// fragment-layout strides (in shorts)
#define E2F_NSTR 589824     // (HWp/32) kb * 4 frags * 64 lanes * 8
#define AVF_NSTR 1179648    // (HWp/32) kb * 8 frags * 64 lanes * 8

typedef short s16x8 __attribute__((ext_vector_type(8)));
typedef unsigned short u16x8 __attribute__((ext_vector_type(8)));
typedef float fx4 __attribute__((ext_vector_type(4)));

__device__ __forceinline__ unsigned short f2bf(float f) {
    union { float f; unsigned int u; } cv; cv.f = f;
    unsigned int u = cv.u;
    u += 0x7FFFu + ((u >> 16) & 1u);
    return (unsigned short)(u >> 16);
}

__device__ __forceinline__ float fexp2(float x) {
    float r; asm("v_exp_f32 %0, %1" : "=v"(r) : "v"(x)); return r;
}

__device__ __forceinline__ unsigned int cvt_pk_bf16(float lo, float hi) {
    unsigned int r; asm("v_cvt_pk_bf16_f32 %0, %1, %2" : "=v"(r) : "v"(lo), "v"(hi)); return r;
}

__device__ __forceinline__ const float* uniform_ptr(const float* p) {
    unsigned long long v = (unsigned long long)(uintptr_t)p;
    unsigned int lo = __builtin_amdgcn_readfirstlane((unsigned int)v);
    unsigned int hi = __builtin_amdgcn_readfirstlane((unsigned int)(v >> 32));
    return (const float*)(uintptr_t)(((unsigned long long)hi << 32) | lo);
}

// Projections. R8-VERBATIM (passing). E1 row-major (log2e-scaled);
// E2 -> e2f fragment layout; AV -> avf fragment layout.
__global__ __launch_bounds__(256) void proj_kernel(
    const float* __restrict__ x,
    const float* __restrict__ w1, const float* __restrict__ b1, const float* __restrict__ a1,
    const float* __restrict__ w2, const float* __restrict__ b2, const float* __restrict__ a2,
    const float* __restrict__ wa, const float* __restrict__ ba, const float* __restrict__ aa,
    unsigned short* __restrict__ e1, unsigned short* __restrict__ e2f,
    unsigned short* __restrict__ avf)
{
    const int n = blockIdx.y;
    const int p0 = blockIdx.x * 64;
    const int wv = threadIdx.x >> 6;
    const int lane = threadIdx.x & 63;
    const int p = p0 + lane;
    const int row0 = blockIdx.z * 64 + wv * 16;   // 0..255 in [e1(64) | e2(64) | av(128)]
    const float* __restrict__ xb = x + (size_t)n * CD * HWp;

    const float* W; const float* B; const float* A; int r0; int mode; float oscale = 1.0f;
    if (row0 < 64)       { W = w1; B = b1; A = a1; r0 = row0;       mode = 0; oscale = LOG2E; }
    else if (row0 < 128) { W = w2; B = b2; A = a2; r0 = row0 - 64;  mode = 1; }
    else                 { W = wa; B = ba; A = aa; r0 = row0 - 128; mode = 2; }
    W = uniform_ptr(W); B = uniform_ptr(B);
    const float slope = A[0];

    float acc[16];
#pragma unroll
    for (int j = 0; j < 16; ++j) acc[j] = B[r0 + j];
    for (int cc = 0; cc < 4; ++cc) {
        float xr[32];
#pragma unroll
        for (int i = 0; i < 32; ++i) xr[i] = xb[(size_t)(cc * 32 + i) * HWp + p];
#pragma unroll
        for (int j = 0; j < 16; ++j) {
            const float* Wr = W + (size_t)(r0 + j) * CD + cc * 32;
            float a = acc[j];
#pragma unroll
            for (int i = 0; i < 32; ++i) a = __builtin_fmaf(Wr[i], xr[i], a);
            acc[j] = a;
        }
    }
#pragma unroll
    for (int j = 0; j < 16; ++j) {
        float v = acc[j];
        acc[j] = (v >= 0.f ? v : slope * v) * oscale;
    }
    if (mode == 0) {
        u16x8 s0, s1;
#pragma unroll
        for (int j = 0; j < 8; ++j) { s0[j] = f2bf(acc[j]); s1[j] = f2bf(acc[8 + j]); }
        unsigned short* dst = e1 + ((size_t)n * HWp + p) * RC + r0;
        *(u16x8*)(dst) = s0;
        *(u16x8*)(dst + 8) = s1;
    } else if (mode == 1) {
        u16x8 s0, s1;
#pragma unroll
        for (int j = 0; j < 8; ++j) { s0[j] = f2bf(acc[j]); s1[j] = f2bf(acc[8 + j]); }
        const int kb = p >> 5, kk = p & 31;
        const int l15w = ((kk >> 3) << 2) | (kk & 3);
        const int hw = (kk >> 2) & 1;
        const int ch = r0 >> 5;
        const int gA = (r0 >> 3) & 3;
        unsigned short* dst = e2f + (size_t)n * E2F_NSTR
                            + ((size_t)((kb * 4 + hw * 2 + ch) * 64 + gA * 16 + l15w)) * 8;
        *(u16x8*)(dst) = s0;          // octet gA   (chan r0+j)
        *(u16x8*)(dst + 128) = s1;    // octet gA+1 (chan r0+8+j)
    } else {
        const int kb = p >> 5, gw = (p >> 3) & 3, jj = p & 7;
        const int ct = r0 >> 4;
        unsigned short* base = avf + (size_t)n * AVF_NSTR
                             + ((size_t)((kb * 8 + ct) * 64 + gw * 16)) * 8 + jj;
#pragma unroll
        for (int j = 0; j < 16; ++j)       // l15 = j (chan r0+j), stride 8 shorts
            base[j * 8] = f2bf(acc[j]);
    }
}

// Flash attention: R2 structure (32 q/wave, 8-wave key-split, 576 blocks) +
// R8 fragment-layout loads + explicit MLP: all 8 af loads issued at step top,
// kf prefetched one step ahead. No LDS tiles. launch_bounds(512,1).
__global__ __launch_bounds__(512, 1) void attn_kernel(
    const unsigned short* __restrict__ e1,
    const unsigned short* __restrict__ e2f,
    const unsigned short* __restrict__ avf,
    float* __restrict__ out)
{
    const int wv = threadIdx.x >> 6;
    const int lane = threadIdx.x & 63;
    const int g = lane >> 4;
    const int l15 = lane & 15;

    // XCD swizzle (R2-verbatim): batch 0 -> XCDs 0-3, batch 1 -> XCDs 4-7
    const int bid = blockIdx.x;
    const int xcd = bid & 7;
    const int n = xcd >> 2;
    const int qslot = (xcd & 3) * 72 + (bid >> 3);   // [0,288)
    const int qb = qslot * 32;

    const unsigned short* __restrict__ E1 = e1 + (size_t)n * HWp * RC;
    const unsigned short* __restrict__ E2F = e2f + (size_t)n * E2F_NSTR;
    const unsigned short* __restrict__ AVF = avf + (size_t)n * AVF_NSTR;

    // Q fragments (B operand): col = query = l15, k = channel = ch*32 + g*8 + j
    s16x8 qf[2][2];
#pragma unroll
    for (int qc = 0; qc < 2; ++qc)
#pragma unroll
        for (int ch = 0; ch < 2; ++ch)
            qf[qc][ch] = *(const s16x8*)(E1 + ((size_t)(qb + qc * 16 + l15)) * RC + ch * 32 + g * 8);

    s16x8 ones;
#pragma unroll
    for (int j = 0; j < 8; ++j) ones[j] = (short)0x3F80;   // bf16 1.0

    fx4 oacc[2][8];
    fx4 lacc[2];
#pragma unroll
    for (int qc = 0; qc < 2; ++qc) {
        lacc[qc] = (fx4){0.f, 0.f, 0.f, 0.f};
#pragma unroll
        for (int ct = 0; ct < 8; ++ct) oacc[qc][ct] = (fx4){0.f, 0.f, 0.f, 0.f};
    }
    float m_run[2] = {-1e30f, -1e30f};

    const int kb0 = wv * NSTEPS;   // first key-block of this wave

    // prologue: prefetch kf for kb0
    s16x8 kfc[2][2];
#pragma unroll
    for (int h = 0; h < 2; ++h)
#pragma unroll
        for (int ch = 0; ch < 2; ++ch)
            kfc[h][ch] = *(const s16x8*)(E2F + ((size_t)((kb0 * 4 + h * 2 + ch) * 64 + lane)) * 8);

    union { s16x8 v; unsigned int w[4]; } pf[2];

    for (int kt = 0; kt < NSTEPS; ++kt) {
        const int kb = kb0 + kt;
        const int kbn = (kt + 1 < NSTEPS) ? kb + 1 : kb;

        // 1) issue ALL af loads for CURRENT kb (fly during QK+softmax)
        s16x8 af[8];
#pragma unroll
        for (int ct = 0; ct < 8; ++ct)
            af[ct] = *(const s16x8*)(AVF + ((size_t)((kb * 8 + ct) * 64 + lane)) * 8);

        // 2) issue kf prefetch for NEXT step
        s16x8 kfn[2][2];
#pragma unroll
        for (int h = 0; h < 2; ++h)
#pragma unroll
            for (int ch = 0; ch < 2; ++ch)
                kfn[h][ch] = *(const s16x8*)(E2F + ((size_t)((kbn * 4 + h * 2 + ch) * 64 + lane)) * 8);

        // 3) QK with current (prefetched) kf — no wait
        fx4 s[2][2];
#pragma unroll
        for (int qc = 0; qc < 2; ++qc)
#pragma unroll
            for (int h = 0; h < 2; ++h) {
                fx4 a = (fx4){0.f, 0.f, 0.f, 0.f};
                a = __builtin_amdgcn_mfma_f32_16x16x32_bf16(kfc[h][0], qf[qc][0], a, 0, 0, 0);
                a = __builtin_amdgcn_mfma_f32_16x16x32_bf16(kfc[h][1], qf[qc][1], a, 0, 0, 0);
                s[qc][h] = a;
            }

        // 4) online softmax (R2-verbatim)
#pragma unroll
        for (int qc = 0; qc < 2; ++qc) {
            float tmax = s[qc][0][0];
#pragma unroll
            for (int h = 0; h < 2; ++h)
#pragma unroll
                for (int r = 0; r < 4; ++r) tmax = fmaxf(tmax, s[qc][h][r]);
            tmax = fmaxf(tmax, __shfl_xor(tmax, 16));
            tmax = fmaxf(tmax, __shfl_xor(tmax, 32));
            if (!__all(tmax - m_run[qc] <= THR_LOG2)) {   // defer-max (T13)
                float mn = fmaxf(m_run[qc], tmax);
                float sc = fexp2(m_run[qc] - mn);
                m_run[qc] = mn;
                lacc[qc][0] *= sc; lacc[qc][1] *= sc; lacc[qc][2] *= sc; lacc[qc][3] *= sc;
#pragma unroll
                for (int ct = 0; ct < 8; ++ct) {
                    oacc[qc][ct][0] *= sc; oacc[qc][ct][1] *= sc;
                    oacc[qc][ct][2] *= sc; oacc[qc][ct][3] *= sc;
                }
            }
            const float m = m_run[qc];
            float p0 = fexp2(s[qc][0][0] - m);
            float p1 = fexp2(s[qc][0][1] - m);
            float p2 = fexp2(s[qc][0][2] - m);
            float p3 = fexp2(s[qc][0][3] - m);
            float p4 = fexp2(s[qc][1][0] - m);
            float p5 = fexp2(s[qc][1][1] - m);
            float p6 = fexp2(s[qc][1][2] - m);
            float p7 = fexp2(s[qc][1][3] - m);
            pf[qc].w[0] = cvt_pk_bf16(p0, p1);
            pf[qc].w[1] = cvt_pk_bf16(p2, p3);
            pf[qc].w[2] = cvt_pk_bf16(p4, p5);
            pf[qc].w[3] = cvt_pk_bf16(p6, p7);
            // l via ones-row MFMA (rescale applies automatically with oacc)
            lacc[qc] = __builtin_amdgcn_mfma_f32_16x16x32_bf16(ones, pf[qc].v, lacc[qc], 0, 0, 0);
        }

        // 5) PV with af (arrived during QK+softmax)
#pragma unroll
        for (int ct = 0; ct < 8; ++ct) {
            oacc[0][ct] = __builtin_amdgcn_mfma_f32_16x16x32_bf16(af[ct], pf[0].v, oacc[0][ct], 0, 0, 0);
            oacc[1][ct] = __builtin_amdgcn_mfma_f32_16x16x32_bf16(af[ct], pf[1].v, oacc[1][ct], 0, 0, 0);
        }

        // 6) rotate kf prefetch
#pragma unroll
        for (int h = 0; h < 2; ++h)
#pragma unroll
            for (int ch = 0; ch < 2; ++ch)
                kfc[h][ch] = kfn[h][ch];
    }

    // ---- cross-wave combine (key-split), R2-verbatim ----
    __shared__ float OA[32][CD + 4];
    __shared__ float MM[KSPLIT][32];
    __shared__ float LL[KSPLIT][32];
    __shared__ float LG[32];

    if (g == 0) {
#pragma unroll
        for (int qc = 0; qc < 2; ++qc) {
            MM[wv][qc * 16 + l15] = m_run[qc];
            LL[wv][qc * 16 + l15] = lacc[qc][0];
        }
    }
    __syncthreads();
    float fsc[2];
#pragma unroll
    for (int qc = 0; qc < 2; ++qc) {
        int q = qc * 16 + l15;
        float mg = MM[0][q];
#pragma unroll
        for (int w = 1; w < KSPLIT; ++w) mg = fmaxf(mg, MM[w][q]);
        fsc[qc] = fexp2(m_run[qc] - mg);
    }
    if (threadIdx.x < 32) {
        int q = threadIdx.x;
        float mg = MM[0][q];
#pragma unroll
        for (int w = 1; w < KSPLIT; ++w) mg = fmaxf(mg, MM[w][q]);
        float ls = 0.f;
#pragma unroll
        for (int w = 0; w < KSPLIT; ++w) ls += fexp2(MM[w][q] - mg) * LL[w][q];
        LG[q] = ls;
    }
    for (int w = 0; w < KSPLIT; ++w) {
        if (wv == w) {
#pragma unroll
            for (int qc = 0; qc < 2; ++qc)
#pragma unroll
                for (int ct = 0; ct < 8; ++ct)
#pragma unroll
                    for (int r = 0; r < 4; ++r) {
                        int q = qc * 16 + l15;
                        int c = ct * 16 + g * 4 + r;
                        float v = oacc[qc][ct][r] * fsc[qc];
                        if (w == 0) OA[q][c] = v; else OA[q][c] += v;
                    }
        }
        __syncthreads();
    }
    {
        const int c = threadIdx.x >> 2;
        const int qh = (threadIdx.x & 3) * 8;
        float* __restrict__ dst = out + ((size_t)n * CD + c) * HWp + qb + qh;
#pragma unroll
        for (int j = 0; j < 8; ++j) dst[j] = OA[qh + j][c] / LG[qh + j];
    }
}

extern "C" void kernel_launch(void* const* d_in, const int* in_sizes, int n_in,
                              void* d_out, int out_size, void* d_ws, size_t ws_size,
                              hipStream_t stream) {
    const float* x  = (const float*)d_in[0];
    const float* w1 = (const float*)d_in[1];
    const float* b1 = (const float*)d_in[2];
    const float* a1 = (const float*)d_in[3];
    const float* w2 = (const float*)d_in[4];
    const float* b2 = (const float*)d_in[5];
    const float* a2 = (const float*)d_in[6];
    const float* wa = (const float*)d_in[7];
    const float* ba = (const float*)d_in[8];
    const float* aa = (const float*)d_in[9];
    float* out = (float*)d_out;

    char* ws = (char*)d_ws;
    unsigned short* e1  = (unsigned short*)ws;                 // [N][HW][64] bf16 (log2e-scaled)
    unsigned short* e2f = (unsigned short*)(ws + 2359296);     // fragment layout
    unsigned short* avf = (unsigned short*)(ws + 4718592);     // fragment layout
    // total ws usage: 9,437,184 B (proven safe)

    dim3 pg(HWp / 64, NB, 4);
    proj_kernel<<<pg, 256, 0, stream>>>(x, w1, b1, a1, w2, b2, a2, wa, ba, aa, e1, e2f, avf);
    attn_kernel<<<dim3(576), 512, 0, stream>>>(e1, e2f, avf, out);
}